// Round 13
// baseline (450.249 us; speedup 1.0000x reference)
//
#include <hip/hip_runtime.h>
#include <stdint.h>

#define T_SEQ   2048
#define D_MODEL 1024
#define N_HEADS 16
#define D_HEAD  64
#define FF_DIM  4096
#define BATCH   2
#define BT      (BATCH * T_SEQ)   // 4096

// Q prescale: 0.125 (1/sqrt(dk)) * log2(e), folded into the QKV epilogue.
#define QSCALE 0.18033688011112042f

typedef unsigned short u16;
typedef __attribute__((ext_vector_type(8))) short bf16x8;
typedef __attribute__((ext_vector_type(4))) float f32x4;
typedef __attribute__((ext_vector_type(16))) float f32x16;

__device__ __forceinline__ u16 f2bf(float f) {
  union { float f; unsigned u; } x; x.f = f;
  unsigned r = x.u + 0x7fffu + ((x.u >> 16) & 1u);
  return (u16)(r >> 16);
}

__device__ __forceinline__ float bf2f(u16 b) {
  union { unsigned u; float f; } x; x.u = ((unsigned)b) << 16;
  return x.f;
}

__device__ __forceinline__ void gload16(const void* g, void* l) {
  __builtin_amdgcn_global_load_lds(
      (const __attribute__((address_space(1))) void*)g,
      (__attribute__((address_space(3))) void*)l, 16, 0, 0);
}

// ---------------------------------------------------------------- fused prep
struct PrepArgs {
  const float* x; u16* xb;
  const float *Wq, *Wk, *Wv, *Wo, *W1, *W2;
  u16 *WqT, *WkT, *WvT, *WoT, *W1T, *W2T;
};

__global__ __launch_bounds__(256)
void prep_kernel(PrepArgs pa) {
  const int bid = blockIdx.x;
  const int tid = threadIdx.x;
  if (bid < 4096) {
    int i = (bid * 256 + tid) * 4;
    float4 v = *(const float4*)(pa.x + i);
    ushort4 o; o.x = f2bf(v.x); o.y = f2bf(v.y); o.z = f2bf(v.z); o.w = f2bf(v.w);
    *(ushort4*)(pa.xb + i) = o;
    return;
  }
  int t = bid - 4096;
  const float* W; u16* Wt; int K, N, rel;
  if (t < 1024)      { W = pa.Wq; Wt = pa.WqT; K = 1024; N = 1024; rel = t; }
  else if (t < 2048) { W = pa.Wk; Wt = pa.WkT; K = 1024; N = 1024; rel = t - 1024; }
  else if (t < 3072) { W = pa.Wv; Wt = pa.WvT; K = 1024; N = 1024; rel = t - 2048; }
  else if (t < 4096) { W = pa.Wo; Wt = pa.WoT; K = 1024; N = 1024; rel = t - 3072; }
  else if (t < 8192) { W = pa.W1; Wt = pa.W1T; K = 1024; N = 4096; rel = t - 4096; }
  else               { W = pa.W2; Wt = pa.W2T; K = 4096; N = 1024; rel = t - 8192; }
  const int ntn = N >> 5;
  const int n0 = (rel % ntn) * 32, k0 = (rel / ntn) * 32;
  const int tx = tid & 31, ty = tid >> 5;  // (32, 8)
  __shared__ float tile[32][33];
#pragma unroll
  for (int r = 0; r < 4; ++r)
    tile[ty + r * 8][tx] = W[(size_t)(k0 + ty + r * 8) * N + n0 + tx];
  __syncthreads();
#pragma unroll
  for (int r = 0; r < 4; ++r)
    Wt[(size_t)(n0 + ty + r * 8) * K + k0 + tx] = f2bf(tile[tx][ty + r * 8]);
}

// ---------------------------------------------------------------- GEMM
// EPI 0: qkv (z picks W/bias/out; q,k -> [b,h,t,dk]; v -> [b,h,dk,t]) bf16;
//        z==0 (Q) additionally scaled by QSCALE.
// EPI 2: bf16 out = relu(C + bias)
// EPI 3: split-K=2: z = k-chunk; raw f32 partial -> out0 + z*M*N
struct GemmArgs {
  const u16* A;
  const u16* B0; const u16* B1; const u16* B2;
  const float* bias0; const float* bias1; const float* bias2;
  void* out0; void* out1; void* out2;
  int M, N, K;
};

template <int EPI>
__global__ __launch_bounds__(256, 3)
void gemm_bt(GemmArgs ga) {
  const int tid = threadIdx.x;
  // XCD-chunked bijective swizzle over the flattened grid (nwg % 8 == 0).
  const int gx = gridDim.x, gy = gridDim.y;
  const int nwg = gx * gy * gridDim.z;
  const int orig = blockIdx.x + gx * (blockIdx.y + gy * blockIdx.z);
  const int swz = (orig & 7) * (nwg >> 3) + (orig >> 3);
  const int bx = swz % gx, by = (swz / gx) % gy, bz = swz / (gx * gy);
  const int m0 = by * 128;
  const int n0 = bx * 128;
  const int lane = tid & 63, w = tid >> 6;
  const int wr = w >> 1, wc = w & 1;
  const int l15 = lane & 15, g = lane >> 4;

  const u16* Bt; const float* bias; void* outp;
  int z = 0;
  if (EPI == 0) {
    z = bz;
    Bt   = (z == 0) ? ga.B0   : (z == 1) ? ga.B1   : ga.B2;
    bias = (z == 0) ? ga.bias0 : (z == 1) ? ga.bias1 : ga.bias2;
    outp = (z == 0) ? ga.out0 : (z == 1) ? ga.out1 : ga.out2;
  } else if (EPI == 3) {
    z = bz; Bt = ga.B0; bias = nullptr; outp = ga.out0;
  } else { Bt = ga.B0; bias = ga.bias0; outp = ga.out0; }

  __shared__ char lsA[128 * 128];  // [128 m][64 k] bf16, rows 128B, XOR-swizzled
  __shared__ char lsB[128 * 128];  // [128 n][64 k] bf16

  f32x4 acc[4][4] = {};
  const int K = ga.K;
  const int kbase = (EPI == 3) ? z * (K >> 1) : 0;
  const int nk = (EPI == 3) ? (K >> 7) : (K >> 6);

  auto stage = [&](int kt) {
    const int k0 = kbase + kt * 64;
#pragma unroll
    for (int i = 0; i < 4; ++i) {
      int o = i * 4096 + tid * 16;
      int row = o >> 7, cb = o & 127;
      int lcb = cb ^ ((row & 7) << 4);
      gload16((const char*)ga.A + ((size_t)(m0 + row) * K + k0) * 2 + lcb, lsA + o);
    }
#pragma unroll
    for (int i = 0; i < 4; ++i) {
      int o = i * 4096 + tid * 16;
      int row = o >> 7, cb = o & 127;
      int lcb = cb ^ ((row & 7) << 4);
      gload16((const char*)Bt + ((size_t)(n0 + row) * K + k0) * 2 + lcb, lsB + o);
    }
  };

  stage(0);
  for (int kt = 0; kt < nk; ++kt) {
    __syncthreads();  // drains vmcnt(0): staged tile visible
#pragma unroll
    for (int kk = 0; kk < 2; ++kk) {
      bf16x8 a[4], b[4];
#pragma unroll
      for (int mi = 0; mi < 4; ++mi) {
        int row = wr * 64 + mi * 16 + l15;
        a[mi] = *(const bf16x8*)(lsA + row * 128 + ((kk * 64 + g * 16) ^ ((row & 7) << 4)));
      }
#pragma unroll
      for (int ni = 0; ni < 4; ++ni) {
        int row = wc * 64 + ni * 16 + l15;
        b[ni] = *(const bf16x8*)(lsB + row * 128 + ((kk * 64 + g * 16) ^ ((row & 7) << 4)));
      }
#pragma unroll
      for (int mi = 0; mi < 4; ++mi)
#pragma unroll
        for (int ni = 0; ni < 4; ++ni)
          acc[mi][ni] = __builtin_amdgcn_mfma_f32_16x16x32_bf16(a[mi], b[ni], acc[mi][ni], 0, 0, 0);
    }
    __syncthreads();  // all reads done before restage
    if (kt + 1 < nk) stage(kt + 1);
  }

  // epilogue
  const int N = ga.N;
#pragma unroll
  for (int mi = 0; mi < 4; ++mi) {
#pragma unroll
    for (int ni = 0; ni < 4; ++ni) {
      const int c = n0 + wc * 64 + ni * 16 + l15;
      const float bv = (EPI == 3) ? 0.0f : bias[c];
#pragma unroll
      for (int j = 0; j < 4; ++j) {
        const int r = m0 + wr * 64 + mi * 16 + g * 4 + j;
        float v = acc[mi][ni][j] + bv;
        if constexpr (EPI == 0) {
          if (z == 0) v *= QSCALE;  // fold 1/sqrt(dk)*log2(e) into Q
          const int bb = r >> 11, t = r & 2047, hh = c >> 6, dk = c & 63;
          u16* o = (u16*)outp;
          size_t idx = (z < 2)
              ? ((size_t)((bb * N_HEADS + hh) * T_SEQ + t)) * D_HEAD + dk
              : ((size_t)((bb * N_HEADS + hh) * D_HEAD + dk)) * T_SEQ + t;
          o[idx] = f2bf(v);
        } else if constexpr (EPI == 3) {
          ((float*)outp)[(size_t)z * ga.M * N + (size_t)r * N + c] = v;
        } else {
          ((u16*)outp)[(size_t)r * N + c] = f2bf(fmaxf(v, 0.0f));
        }
      }
    }
  }
}

// ---------------------------------------------------------------- attn flash
// Single sweep (no max-sub; logits bounded): accumulate UNNORMALIZED p into
// PV and lsum simultaneously; normalize vacc at the end; write den for the
// score kernel. R8 per-wave machinery (32x32 MFMA, KVBLK=128, lsP round-trip)
// minus the score store and minus the entire old sweep A.
// C-layout (m74/m101): col=lane&31, row=(reg&3)+8*(reg>>2)+4*(lane>>5).
__global__ __launch_bounds__(128, 2)
void attn_flash(const u16* __restrict__ q, const u16* __restrict__ k,
                const u16* __restrict__ vT, float* __restrict__ den,
                u16* __restrict__ val) {
  const int tid = threadIdx.x;
  const int lane = tid & 63, w = tid >> 6;   // 2 waves
  const int l31 = lane & 31, hi = lane >> 5;
  const int nwg = gridDim.x;   // 1024
  const int orig = blockIdx.x;
  const int swz = (orig & 7) * (nwg >> 3) + (orig >> 3);
  const int bh = swz >> 5;
  const int Q0 = (swz & 31) * 64;
  const size_t hoff = (size_t)bh * T_SEQ * D_HEAD;
  const u16* qb = q + hoff;
  const u16* kb = k + hoff;     // [2048 t][64 dk]
  const u16* vb = vT + hoff;    // [64 dk][2048 t]

  __shared__ char lsK[128 * 128];   // [128 j][64 dk] bf16, rows 128B, xor (r&7)<<4
  __shared__ char lsV[64 * 256];    // [64 dk][128 j] bf16, rows 256B, xor (r&15)<<4
  __shared__ char lsP[2][32 * 128]; // per-wave [32 q][64 j] bf16, rows 128B, xor (r&7)<<4

  auto stageK = [&](int jt) {
    const int J0 = jt * 128;
#pragma unroll
    for (int i = 0; i < 8; ++i) {
      int o = i * 2048 + tid * 16;
      int row = o >> 7, cb = o & 127;
      int lcb = cb ^ ((row & 7) << 4);
      gload16((const char*)kb + ((size_t)(J0 + row) * D_HEAD) * 2 + lcb, lsK + o);
    }
  };
  auto stageV = [&](int jt) {
    const int J0 = jt * 128;
#pragma unroll
    for (int i = 0; i < 8; ++i) {
      int o = i * 2048 + tid * 16;
      int row = o >> 8, cb = o & 255;
      int lcb = cb ^ ((row & 15) << 4);
      gload16((const char*)vb + ((size_t)row * T_SEQ + J0) * 2 + lcb, lsV + o);
    }
  };

  bf16x8 qf[4];
  {
    int row = Q0 + w * 32 + l31;
#pragma unroll
    for (int ks = 0; ks < 4; ++ks)
      qf[ks] = *(const bf16x8*)(qb + (size_t)row * D_HEAD + ks * 16 + hi * 8);
  }

  float lsum[16];
#pragma unroll
  for (int r = 0; r < 16; ++r) lsum[r] = 0.f;
  f32x16 vacc[2] = {};
  char* myP = lsP[w];

  for (int jt = 0; jt < 16; ++jt) {
    __syncthreads();
    stageK(jt);
    stageV(jt);
    __syncthreads();
#pragma unroll
    for (int h = 0; h < 2; ++h) {
#pragma unroll
      for (int st = 0; st < 2; ++st) {
        f32x16 c = {};
        __builtin_amdgcn_s_setprio(1);
#pragma unroll
        for (int ks = 0; ks < 4; ++ks) {
          int row = h * 64 + st * 32 + l31;
          bf16x8 b = *(const bf16x8*)(lsK + row * 128 + ((ks * 32 + hi * 16) ^ ((row & 7) << 4)));
          c = __builtin_amdgcn_mfma_f32_32x32x16_bf16(qf[ks], b, c, 0, 0, 0);
        }
        __builtin_amdgcn_s_setprio(0);
#pragma unroll
        for (int r = 0; r < 16; ++r) {
          int rr = (r & 3) + 8 * (r >> 2) + 4 * hi;  // local q row 0..31
          float p = __builtin_amdgcn_exp2f(c[r]);    // unnormalized
          lsum[r] += p;
          *(u16*)(myP + rr * 128 + (((st * 32 + l31) * 2) ^ ((rr & 7) << 4))) = f2bf(p);
        }
      }
      // PV for this half: k-dim = 64 local j (4 ksteps of 16)
#pragma unroll
      for (int ks = 0; ks < 4; ++ks) {
        bf16x8 pa = *(const bf16x8*)(myP + l31 * 128 + ((ks * 32 + hi * 16) ^ ((l31 & 7) << 4)));
        __builtin_amdgcn_s_setprio(1);
#pragma unroll
        for (int ct = 0; ct < 2; ++ct) {
          int vrow = ct * 32 + l31;
          bf16x8 vf = *(const bf16x8*)(lsV + vrow * 256 +
                                       ((h * 128 + ks * 32 + hi * 16) ^ ((vrow & 15) << 4)));
          vacc[ct] = __builtin_amdgcn_mfma_f32_32x32x16_bf16(pa, vf, vacc[ct], 0, 0, 0);
        }
        __builtin_amdgcn_s_setprio(0);
      }
    }
  }

  // reduce lsum over the 32-lane j dimension -> den per q-row
  float inv[16];
#pragma unroll
  for (int r = 0; r < 16; ++r) {
    float v = lsum[r];
    v += __shfl_xor(v, 1);
    v += __shfl_xor(v, 2);
    v += __shfl_xor(v, 4);
    v += __shfl_xor(v, 8);
    v += __shfl_xor(v, 16);
    int rr = (r & 3) + 8 * (r >> 2) + 4 * hi;
    if (l31 == 0) den[(size_t)bh * T_SEQ + Q0 + w * 32 + rr] = v;
    inv[r] = 1.0f / v;
  }

  const int bb = bh >> 4, hh = bh & 15;
#pragma unroll
  for (int ct = 0; ct < 2; ++ct)
#pragma unroll
    for (int r = 0; r < 16; ++r) {
      int rr = (r & 3) + 8 * (r >> 2) + 4 * hi;
      int qrow = Q0 + w * 32 + rr;
      val[((size_t)(bb * T_SEQ + qrow)) * D_MODEL + hh * D_HEAD + ct * 32 + l31] =
          f2bf(vacc[ct][r] * inv[r]);
    }
}

// ---------------------------------------------------------------- score
// Lean store-stream kernel: 512 blocks (bh-major XCD swizzle), 256 thr = 4
// waves, each wave 32 q-rows (QBLK=128). K-only LDS (16KB) -> high occupancy;
// QK^T -> exp2 -> *inv(den) -> nontemporal coalesced store. No PV, no lsP.
__global__ __launch_bounds__(256, 4)
void score_kernel(const u16* __restrict__ q, const u16* __restrict__ k,
                  const float* __restrict__ den, float* __restrict__ score) {
  const int tid = threadIdx.x;
  const int lane = tid & 63, w = tid >> 6;   // 4 waves
  const int l31 = lane & 31, hi = lane >> 5;
  const int nwg = gridDim.x;   // 512
  const int orig = blockIdx.x;
  const int swz = (orig & 7) * (nwg >> 3) + (orig >> 3);
  const int bh = swz >> 4;           // 16 q-blocks per head, consecutive
  const int Qb = (swz & 15) * 128;
  const size_t hoff = (size_t)bh * T_SEQ * D_HEAD;
  const u16* qb = q + hoff;
  const u16* kb = k + hoff;
  float* sb = score + ((size_t)bh * T_SEQ + Qb) * T_SEQ;

  __shared__ char lsK[128 * 128];   // [128 j][64 dk] bf16, rows 128B, xor (r&7)<<4

  bf16x8 qf[4];
  {
    int row = Qb + w * 32 + l31;
#pragma unroll
    for (int ks = 0; ks < 4; ++ks)
      qf[ks] = *(const bf16x8*)(qb + (size_t)row * D_HEAD + ks * 16 + hi * 8);
  }

  float inv[16];
#pragma unroll
  for (int r = 0; r < 16; ++r) {
    int rr = (r & 3) + 8 * (r >> 2) + 4 * hi;
    inv[r] = 1.0f / den[(size_t)bh * T_SEQ + Qb + w * 32 + rr];
  }

  for (int jt = 0; jt < 16; ++jt) {
    const int J0 = jt * 128;
    __syncthreads();
#pragma unroll
    for (int i = 0; i < 4; ++i) {
      int o = i * 4096 + tid * 16;
      int row = o >> 7, cb = o & 127;
      int lcb = cb ^ ((row & 7) << 4);
      gload16((const char*)kb + ((size_t)(J0 + row) * D_HEAD) * 2 + lcb, lsK + o);
    }
    __syncthreads();
#pragma unroll
    for (int st = 0; st < 4; ++st) {
      f32x16 c = {};
      __builtin_amdgcn_s_setprio(1);
#pragma unroll
      for (int ks = 0; ks < 4; ++ks) {
        int row = st * 32 + l31;
        bf16x8 b = *(const bf16x8*)(lsK + row * 128 + ((ks * 32 + hi * 16) ^ ((row & 7) << 4)));
        c = __builtin_amdgcn_mfma_f32_32x32x16_bf16(qf[ks], b, c, 0, 0, 0);
      }
      __builtin_amdgcn_s_setprio(0);
#pragma unroll
      for (int r = 0; r < 16; ++r) {
        int rr = (r & 3) + 8 * (r >> 2) + 4 * hi;
        float p = __builtin_amdgcn_exp2f(c[r]) * inv[r];
        __builtin_nontemporal_store(
            p, &sb[(size_t)(w * 32 + rr) * T_SEQ + J0 + st * 32 + l31]);
      }
    }
  }
}

// ---------------------------------------------------------------- fused split-K reduce + row norm
// v = p0 + p1 + bias + resid ; out = alpha*(v-mu)/(std_unbiased+eps) + beta
template <bool OUT_F32, bool OUT_BF16, bool RESID_BF16>
__global__ __launch_bounds__(256)
void norm_kernel(const float* __restrict__ p0, const float* __restrict__ p1,
                 const float* __restrict__ bias, const float* __restrict__ residf,
                 const u16* __restrict__ residb,
                 const float* __restrict__ alpha, const float* __restrict__ beta,
                 float* __restrict__ outf, u16* __restrict__ outb) {
  const int row = blockIdx.x;
  const int tid = threadIdx.x;
  const size_t base = (size_t)row * D_MODEL + tid * 4;
  float4 v0 = *(const float4*)(p0 + base);
  float4 v1 = *(const float4*)(p1 + base);
  float4 bi = *(const float4*)(bias + tid * 4);
  float4 rs;
  if (RESID_BF16) {
    ushort4 rb = *(const ushort4*)(residb + base);
    rs.x = bf2f(rb.x); rs.y = bf2f(rb.y); rs.z = bf2f(rb.z); rs.w = bf2f(rb.w);
  } else {
    rs = *(const float4*)(residf + base);
  }
  float4 v;
  v.x = v0.x + v1.x + bi.x + rs.x;
  v.y = v0.y + v1.y + bi.y + rs.y;
  v.z = v0.z + v1.z + bi.z + rs.z;
  v.w = v0.w + v1.w + bi.w + rs.w;
  float s = v.x + v.y + v.z + v.w;
  float ss = v.x * v.x + v.y * v.y + v.z * v.z + v.w * v.w;
#pragma unroll
  for (int m = 1; m < 64; m <<= 1) {
    s += __shfl_xor(s, m);
    ss += __shfl_xor(ss, m);
  }
  __shared__ float red[8];
  int w = tid >> 6, lane = tid & 63;
  if (lane == 0) { red[w] = s; red[4 + w] = ss; }
  __syncthreads();
  s = red[0] + red[1] + red[2] + red[3];
  ss = red[4] + red[5] + red[6] + red[7];
  float mu = s * (1.0f / 1024.0f);
  float var = fmaxf(ss - s * mu, 0.0f) * (1.0f / 1023.0f);  // unbiased (ddof=1)
  float inv = 1.0f / (sqrtf(var) + 1e-6f);
  float4 a = *(const float4*)(alpha + tid * 4);
  float4 be = *(const float4*)(beta + tid * 4);
  float4 o;
  o.x = (v.x - mu) * inv * a.x + be.x;
  o.y = (v.y - mu) * inv * a.y + be.y;
  o.z = (v.z - mu) * inv * a.z + be.z;
  o.w = (v.w - mu) * inv * a.w + be.w;
  if (OUT_F32) *(float4*)(outf + base) = o;
  if (OUT_BF16) {
    ushort4 ob; ob.x = f2bf(o.x); ob.y = f2bf(o.y); ob.z = f2bf(o.z); ob.w = f2bf(o.w);
    *(ushort4*)(outb + base) = ob;
  }
}

// ---------------------------------------------------------------- launch
extern "C" void kernel_launch(void* const* d_in, const int* in_sizes, int n_in,
                              void* d_out, int out_size, void* d_ws, size_t ws_size,
                              hipStream_t stream) {
  const float* x   = (const float*)d_in[0];
  const float* Wq  = (const float*)d_in[2];
  const float* bq  = (const float*)d_in[3];
  const float* Wk  = (const float*)d_in[4];
  const float* bk  = (const float*)d_in[5];
  const float* Wv  = (const float*)d_in[6];
  const float* bv  = (const float*)d_in[7];
  const float* Wo  = (const float*)d_in[8];
  const float* bo  = (const float*)d_in[9];
  const float* W1  = (const float*)d_in[10];
  const float* b1  = (const float*)d_in[11];
  const float* W2  = (const float*)d_in[12];
  const float* b2  = (const float*)d_in[13];
  const float* a1  = (const float*)d_in[14];
  const float* be1 = (const float*)d_in[15];
  const float* a2  = (const float*)d_in[16];
  const float* be2 = (const float*)d_in[17];

  float* out   = (float*)d_out;
  float* score = out + (size_t)BT * D_MODEL;

  // ws layout (peak 96 MB):
  char* ws = (char*)d_ws;
  const size_t MB = (size_t)1 << 20;
  u16*   xb   = (u16*)(ws + 0 * MB);    // 8   (dead after qkv) -> xnb
  u16*   xnb  = (u16*)(ws + 0 * MB);    // 8   (norm1 out; resid for norm2)
  u16*   WqT  = (u16*)(ws + 8 * MB);    // 2   (dead after qkv) -> den
  float* denw = (float*)(ws + 8 * MB);  // 0.25 (attn_flash out)
  u16*   WkT  = (u16*)(ws + 10 * MB);   // 2   (dead after qkv)
  u16*   WvT  = (u16*)(ws + 12 * MB);   // 2   (dead after qkv)
  u16*   WoT  = (u16*)(ws + 14 * MB);   // 2   (dead after Wo)
  u16*   W1T  = (u16*)(ws + 16 * MB);   // 8   (dead after ffn1)
  u16*   W2T  = (u16*)(ws + 24 * MB);   // 8   (dead after ffn2)
  u16*   qw   = (u16*)(ws + 32 * MB);   // 8   (dead after score)
  u16*   kw   = (u16*)(ws + 40 * MB);   // 8   (dead after score)
  u16*   vTw  = (u16*)(ws + 48 * MB);   // 8   (dead after attn_flash)
  u16*   valw = (u16*)(ws + 56 * MB);   // 8   (dead after Wo)
  u16*   hw   = (u16*)(ws + 32 * MB);   // 32  (FFN1 out; reuses qw/kw/vTw/valw)
  float* p0   = (float*)(ws + 64 * MB); // 16
  float* p1   = (float*)(ws + 80 * MB); // 16

  // 1) fused prep: x cvt + 6 weight transposes
  {
    PrepArgs pa{ x, xb, Wq, Wk, Wv, Wo, W1, W2, WqT, WkT, WvT, WoT, W1T, W2T };
    prep_kernel<<<16384, 256, 0, stream>>>(pa);
  }

  // 2) QKV projections (one launch, z = q/k/v; Q prescaled by QSCALE)
  {
    GemmArgs ga{};
    ga.A = xb;
    ga.B0 = WqT; ga.B1 = WkT; ga.B2 = WvT;
    ga.bias0 = bq; ga.bias1 = bk; ga.bias2 = bv;
    ga.out0 = qw; ga.out1 = kw; ga.out2 = vTw;
    ga.M = BT; ga.N = D_MODEL; ga.K = D_MODEL;
    gemm_bt<0><<<dim3(8, 32, 3), 256, 0, stream>>>(ga);
  }

  // 3a) flash attention: val + den (no score materialization)
  attn_flash<<<1024, 128, 0, stream>>>(qw, kw, vTw, denw, valw);

  // 3b) score stream: normalized P -> d_out
  score_kernel<<<512, 256, 0, stream>>>(qw, kw, denw, score);

  // 4) Wo projection, split-K=2 -> p0/p1
  {
    GemmArgs ga{};
    ga.A = valw; ga.B0 = WoT; ga.out0 = p0;
    ga.M = BT; ga.N = D_MODEL; ga.K = D_MODEL;
    gemm_bt<3><<<dim3(8, 32, 2), 256, 0, stream>>>(ga);
  }

  // 5) norm1: (p0+p1+bo+x) -> xnb (bf16 only)
  norm_kernel<false, true, false><<<BT, 256, 0, stream>>>(
      p0, p1, bo, x, nullptr, a1, be1, nullptr, xnb);

  // 6) FFN1: relu(xnb @ W1 + b1) -> hw (bf16)
  {
    GemmArgs ga{};
    ga.A = xnb; ga.B0 = W1T; ga.bias0 = b1; ga.out0 = hw;
    ga.M = BT; ga.N = FF_DIM; ga.K = D_MODEL;
    gemm_bt<2><<<dim3(32, 32, 1), 256, 0, stream>>>(ga);
  }

  // 7) FFN2: hw @ W2, split-K=2 -> p0/p1
  {
    GemmArgs ga{};
    ga.A = hw; ga.B0 = W2T; ga.out0 = p0;
    ga.M = BT; ga.N = D_MODEL; ga.K = FF_DIM;
    gemm_bt<3><<<dim3(8, 32, 2), 256, 0, stream>>>(ga);
  }

  // 8) norm2: (p0+p1+b2+xnb) -> out
  norm_kernel<true, false, true><<<BT, 256, 0, stream>>>(
      p0, p1, b2, nullptr, xnb, a2, be2, out, nullptr);
}

// Round 14
// 339.103 us; speedup vs baseline: 1.3278x; 1.3278x over previous
//
#include <hip/hip_runtime.h>
#include <stdint.h>

#define T_SEQ   2048
#define D_MODEL 1024
#define N_HEADS 16
#define D_HEAD  64
#define FF_DIM  4096
#define BATCH   2
#define BT      (BATCH * T_SEQ)   // 4096

// Q prescale: 0.125 (1/sqrt(dk)) * log2(e), folded into the QKV epilogue.
#define QSCALE 0.18033688011112042f

typedef unsigned short u16;
typedef __attribute__((ext_vector_type(8))) short bf16x8;
typedef __attribute__((ext_vector_type(4))) float f32x4;
typedef __attribute__((ext_vector_type(16))) float f32x16;

__device__ __forceinline__ u16 f2bf(float f) {
  union { float f; unsigned u; } x; x.f = f;
  unsigned r = x.u + 0x7fffu + ((x.u >> 16) & 1u);
  return (u16)(r >> 16);
}

__device__ __forceinline__ float bf2f(u16 b) {
  union { unsigned u; float f; } x; x.u = ((unsigned)b) << 16;
  return x.f;
}

__device__ __forceinline__ void gload16(const void* g, void* l) {
  __builtin_amdgcn_global_load_lds(
      (const __attribute__((address_space(1))) void*)g,
      (__attribute__((address_space(3))) void*)l, 16, 0, 0);
}

// ---------------------------------------------------------------- fused prep
struct PrepArgs {
  const float* x; u16* xb;
  const float *Wq, *Wk, *Wv, *Wo, *W1, *W2;
  u16 *WqT, *WkT, *WvT, *WoT, *W1T, *W2T;
};

__global__ __launch_bounds__(256)
void prep_kernel(PrepArgs pa) {
  const int bid = blockIdx.x;
  const int tid = threadIdx.x;
  if (bid < 4096) {
    int i = (bid * 256 + tid) * 4;
    float4 v = *(const float4*)(pa.x + i);
    ushort4 o; o.x = f2bf(v.x); o.y = f2bf(v.y); o.z = f2bf(v.z); o.w = f2bf(v.w);
    *(ushort4*)(pa.xb + i) = o;
    return;
  }
  int t = bid - 4096;
  const float* W; u16* Wt; int K, N, rel;
  if (t < 1024)      { W = pa.Wq; Wt = pa.WqT; K = 1024; N = 1024; rel = t; }
  else if (t < 2048) { W = pa.Wk; Wt = pa.WkT; K = 1024; N = 1024; rel = t - 1024; }
  else if (t < 3072) { W = pa.Wv; Wt = pa.WvT; K = 1024; N = 1024; rel = t - 2048; }
  else if (t < 4096) { W = pa.Wo; Wt = pa.WoT; K = 1024; N = 1024; rel = t - 3072; }
  else if (t < 8192) { W = pa.W1; Wt = pa.W1T; K = 1024; N = 4096; rel = t - 4096; }
  else               { W = pa.W2; Wt = pa.W2T; K = 4096; N = 1024; rel = t - 8192; }
  const int ntn = N >> 5;
  const int n0 = (rel % ntn) * 32, k0 = (rel / ntn) * 32;
  const int tx = tid & 31, ty = tid >> 5;  // (32, 8)
  __shared__ float tile[32][33];
#pragma unroll
  for (int r = 0; r < 4; ++r)
    tile[ty + r * 8][tx] = W[(size_t)(k0 + ty + r * 8) * N + n0 + tx];
  __syncthreads();
#pragma unroll
  for (int r = 0; r < 4; ++r)
    Wt[(size_t)(n0 + ty + r * 8) * K + k0 + tx] = f2bf(tile[tx][ty + r * 8]);
}

// ---------------------------------------------------------------- GEMM
// EPI 0: qkv (z picks W/bias/out; q,k -> [b,h,t,dk]; v -> [b,h,dk,t]) bf16;
//        z==0 (Q) additionally scaled by QSCALE.
// EPI 2: bf16 out = relu(C + bias)
// EPI 3: split-K=2: z = k-chunk; raw f32 partial -> out0 + z*M*N
struct GemmArgs {
  const u16* A;
  const u16* B0; const u16* B1; const u16* B2;
  const float* bias0; const float* bias1; const float* bias2;
  void* out0; void* out1; void* out2;
  int M, N, K;
};

template <int EPI>
__global__ __launch_bounds__(256, 3)
void gemm_bt(GemmArgs ga) {
  const int tid = threadIdx.x;
  // XCD-chunked bijective swizzle over the flattened grid (nwg % 8 == 0).
  const int gx = gridDim.x, gy = gridDim.y;
  const int nwg = gx * gy * gridDim.z;
  const int orig = blockIdx.x + gx * (blockIdx.y + gy * blockIdx.z);
  const int swz = (orig & 7) * (nwg >> 3) + (orig >> 3);
  const int bx = swz % gx, by = (swz / gx) % gy, bz = swz / (gx * gy);
  const int m0 = by * 128;
  const int n0 = bx * 128;
  const int lane = tid & 63, w = tid >> 6;
  const int wr = w >> 1, wc = w & 1;
  const int l15 = lane & 15, g = lane >> 4;

  const u16* Bt; const float* bias; void* outp;
  int z = 0;
  if (EPI == 0) {
    z = bz;
    Bt   = (z == 0) ? ga.B0   : (z == 1) ? ga.B1   : ga.B2;
    bias = (z == 0) ? ga.bias0 : (z == 1) ? ga.bias1 : ga.bias2;
    outp = (z == 0) ? ga.out0 : (z == 1) ? ga.out1 : ga.out2;
  } else if (EPI == 3) {
    z = bz; Bt = ga.B0; bias = nullptr; outp = ga.out0;
  } else { Bt = ga.B0; bias = ga.bias0; outp = ga.out0; }

  __shared__ char lsA[128 * 128];  // [128 m][64 k] bf16, rows 128B, XOR-swizzled
  __shared__ char lsB[128 * 128];  // [128 n][64 k] bf16

  f32x4 acc[4][4] = {};
  const int K = ga.K;
  const int kbase = (EPI == 3) ? z * (K >> 1) : 0;
  const int nk = (EPI == 3) ? (K >> 7) : (K >> 6);

  auto stage = [&](int kt) {
    const int k0 = kbase + kt * 64;
#pragma unroll
    for (int i = 0; i < 4; ++i) {
      int o = i * 4096 + tid * 16;
      int row = o >> 7, cb = o & 127;
      int lcb = cb ^ ((row & 7) << 4);
      gload16((const char*)ga.A + ((size_t)(m0 + row) * K + k0) * 2 + lcb, lsA + o);
    }
#pragma unroll
    for (int i = 0; i < 4; ++i) {
      int o = i * 4096 + tid * 16;
      int row = o >> 7, cb = o & 127;
      int lcb = cb ^ ((row & 7) << 4);
      gload16((const char*)Bt + ((size_t)(n0 + row) * K + k0) * 2 + lcb, lsB + o);
    }
  };

  stage(0);
  for (int kt = 0; kt < nk; ++kt) {
    __syncthreads();  // drains vmcnt(0): staged tile visible
#pragma unroll
    for (int kk = 0; kk < 2; ++kk) {
      bf16x8 a[4], b[4];
#pragma unroll
      for (int mi = 0; mi < 4; ++mi) {
        int row = wr * 64 + mi * 16 + l15;
        a[mi] = *(const bf16x8*)(lsA + row * 128 + ((kk * 64 + g * 16) ^ ((row & 7) << 4)));
      }
#pragma unroll
      for (int ni = 0; ni < 4; ++ni) {
        int row = wc * 64 + ni * 16 + l15;
        b[ni] = *(const bf16x8*)(lsB + row * 128 + ((kk * 64 + g * 16) ^ ((row & 7) << 4)));
      }
#pragma unroll
      for (int mi = 0; mi < 4; ++mi)
#pragma unroll
        for (int ni = 0; ni < 4; ++ni)
          acc[mi][ni] = __builtin_amdgcn_mfma_f32_16x16x32_bf16(a[mi], b[ni], acc[mi][ni], 0, 0, 0);
    }
    __syncthreads();  // all reads done before restage
    if (kt + 1 < nk) stage(kt + 1);
  }

  // epilogue
  const int N = ga.N;
#pragma unroll
  for (int mi = 0; mi < 4; ++mi) {
#pragma unroll
    for (int ni = 0; ni < 4; ++ni) {
      const int c = n0 + wc * 64 + ni * 16 + l15;
      const float bv = (EPI == 3) ? 0.0f : bias[c];
#pragma unroll
      for (int j = 0; j < 4; ++j) {
        const int r = m0 + wr * 64 + mi * 16 + g * 4 + j;
        float v = acc[mi][ni][j] + bv;
        if constexpr (EPI == 0) {
          if (z == 0) v *= QSCALE;  // fold 1/sqrt(dk)*log2(e) into Q
          const int bb = r >> 11, t = r & 2047, hh = c >> 6, dk = c & 63;
          u16* o = (u16*)outp;
          size_t idx = (z < 2)
              ? ((size_t)((bb * N_HEADS + hh) * T_SEQ + t)) * D_HEAD + dk
              : ((size_t)((bb * N_HEADS + hh) * D_HEAD + dk)) * T_SEQ + t;
          o[idx] = f2bf(v);
        } else if constexpr (EPI == 3) {
          ((float*)outp)[(size_t)z * ga.M * N + (size_t)r * N + c] = v;
        } else {
          ((u16*)outp)[(size_t)r * N + c] = f2bf(fmaxf(v, 0.0f));
        }
      }
    }
  }
}

// ---------------------------------------------------------------- attention
// R8/R12 geometry (best known): 1024 blocks XCD-swizzled, 128 thr = 2 waves,
// wave owns 32 q-rows via 32x32x16 MFMA, KVBLK=128, 40KB LDS -> 4 blk/CU.
// Two sweeps in ONE kernel (block-level TLP hides sweep A under other blocks'
// sweep B -- R13 proved splitting loses this). Q prescaled by QSCALE -> exp2.
// C-layout (m74/m101): col=lane&31, row=(reg&3)+8*(reg>>2)+4*(lane>>5).
__global__ __launch_bounds__(128, 2)
void attn_kernel(const u16* __restrict__ q, const u16* __restrict__ k,
                 const u16* __restrict__ vT, float* __restrict__ score,
                 u16* __restrict__ val) {
  const int tid = threadIdx.x;
  const int lane = tid & 63, w = tid >> 6;   // 2 waves
  const int l31 = lane & 31, hi = lane >> 5;
  const int nwg = gridDim.x;   // 1024
  const int orig = blockIdx.x;
  const int swz = (orig & 7) * (nwg >> 3) + (orig >> 3);
  const int bh = swz >> 5;          // 32 q-blocks of one head are consecutive
  const int Q0 = (swz & 31) * 64;
  const size_t hoff = (size_t)bh * T_SEQ * D_HEAD;
  const u16* qb = q + hoff;
  const u16* kb = k + hoff;     // [2048 t][64 dk]
  const u16* vb = vT + hoff;    // [64 dk][2048 t]
  float* sb = score + ((size_t)bh * T_SEQ + Q0) * T_SEQ;

  __shared__ char lsK[128 * 128];   // [128 j][64 dk] bf16, rows 128B, xor (r&7)<<4
  __shared__ char lsV[64 * 256];    // [64 dk][128 j] bf16, rows 256B, xor (r&15)<<4
  __shared__ char lsP[2][32 * 128]; // per-wave [32 q][64 j] bf16, rows 128B, xor (r&7)<<4

  auto stageK = [&](int jt) {
    const int J0 = jt * 128;
#pragma unroll
    for (int i = 0; i < 8; ++i) {
      int o = i * 2048 + tid * 16;
      int row = o >> 7, cb = o & 127;
      int lcb = cb ^ ((row & 7) << 4);
      gload16((const char*)kb + ((size_t)(J0 + row) * D_HEAD) * 2 + lcb, lsK + o);
    }
  };
  auto stageV = [&](int jt) {
    const int J0 = jt * 128;
#pragma unroll
    for (int i = 0; i < 8; ++i) {
      int o = i * 2048 + tid * 16;
      int row = o >> 8, cb = o & 255;
      int lcb = cb ^ ((row & 15) << 4);
      gload16((const char*)vb + ((size_t)row * T_SEQ + J0) * 2 + lcb, lsV + o);
    }
  };

  // Q fragments: A[row=l31][k=ks*16+hi*8 .. +8]
  bf16x8 qf[4];
  {
    int row = Q0 + w * 32 + l31;
#pragma unroll
    for (int ks = 0; ks < 4; ++ks)
      qf[ks] = *(const bf16x8*)(qb + (size_t)row * D_HEAD + ks * 16 + hi * 8);
  }

  float lsum[16];
#pragma unroll
  for (int r = 0; r < 16; ++r) lsum[r] = 0.f;

  // ---- sweep A: row sums of exp ----
  for (int jt = 0; jt < 16; ++jt) {
    __syncthreads();
    stageK(jt);
    __syncthreads();
#pragma unroll
    for (int st = 0; st < 4; ++st) {
      f32x16 c = {};
      __builtin_amdgcn_s_setprio(1);
#pragma unroll
      for (int ks = 0; ks < 4; ++ks) {
        int row = st * 32 + l31;
        bf16x8 b = *(const bf16x8*)(lsK + row * 128 + ((ks * 32 + hi * 16) ^ ((row & 7) << 4)));
        c = __builtin_amdgcn_mfma_f32_32x32x16_bf16(qf[ks], b, c, 0, 0, 0);
      }
      __builtin_amdgcn_s_setprio(0);
#pragma unroll
      for (int r = 0; r < 16; ++r)
        lsum[r] += __builtin_amdgcn_exp2f(c[r]);
    }
  }
  float inv[16];
#pragma unroll
  for (int r = 0; r < 16; ++r) {
    float v = lsum[r];
    v += __shfl_xor(v, 1);
    v += __shfl_xor(v, 2);
    v += __shfl_xor(v, 4);
    v += __shfl_xor(v, 8);
    v += __shfl_xor(v, 16);
    inv[r] = 1.0f / v;
  }

  f32x16 vacc[2] = {};
  char* myP = lsP[w];

  // ---- sweep B: P write + PV ----
  for (int jt = 0; jt < 16; ++jt) {
    const int J0 = jt * 128;
    __syncthreads();
    stageK(jt);
    stageV(jt);
    __syncthreads();
#pragma unroll
    for (int h = 0; h < 2; ++h) {
      // QK^T for this 64-j half: 2 col-subtiles of 32
#pragma unroll
      for (int st = 0; st < 2; ++st) {
        f32x16 c = {};
        __builtin_amdgcn_s_setprio(1);
#pragma unroll
        for (int ks = 0; ks < 4; ++ks) {
          int row = h * 64 + st * 32 + l31;
          bf16x8 b = *(const bf16x8*)(lsK + row * 128 + ((ks * 32 + hi * 16) ^ ((row & 7) << 4)));
          c = __builtin_amdgcn_mfma_f32_32x32x16_bf16(qf[ks], b, c, 0, 0, 0);
        }
        __builtin_amdgcn_s_setprio(0);
#pragma unroll
        for (int r = 0; r < 16; ++r) {
          int rr = (r & 3) + 8 * (r >> 2) + 4 * hi;  // local q row 0..31
          float p = __builtin_amdgcn_exp2f(c[r]) * inv[r];
          __builtin_nontemporal_store(
              p, &sb[(size_t)(w * 32 + rr) * T_SEQ + J0 + h * 64 + st * 32 + l31]);
          *(u16*)(myP + rr * 128 + (((st * 32 + l31) * 2) ^ ((rr & 7) << 4))) = f2bf(p);
        }
      }
      // PV for this half: k-dim = 64 local j (4 ksteps of 16)
#pragma unroll
      for (int ks = 0; ks < 4; ++ks) {
        bf16x8 pa = *(const bf16x8*)(myP + l31 * 128 + ((ks * 32 + hi * 16) ^ ((l31 & 7) << 4)));
        __builtin_amdgcn_s_setprio(1);
#pragma unroll
        for (int ct = 0; ct < 2; ++ct) {
          int vrow = ct * 32 + l31;
          bf16x8 vf = *(const bf16x8*)(lsV + vrow * 256 +
                                       ((h * 128 + ks * 32 + hi * 16) ^ ((vrow & 15) << 4)));
          vacc[ct] = __builtin_amdgcn_mfma_f32_32x32x16_bf16(pa, vf, vacc[ct], 0, 0, 0);
        }
        __builtin_amdgcn_s_setprio(0);
      }
    }
  }

  const int bb = bh >> 4, hh = bh & 15;
#pragma unroll
  for (int ct = 0; ct < 2; ++ct)
#pragma unroll
    for (int r = 0; r < 16; ++r) {
      int rr = (r & 3) + 8 * (r >> 2) + 4 * hi;
      int qrow = Q0 + w * 32 + rr;
      val[((size_t)(bb * T_SEQ + qrow)) * D_MODEL + hh * D_HEAD + ct * 32 + l31] =
          f2bf(vacc[ct][r]);
    }
}

// ---------------------------------------------------------------- fused split-K reduce + row norm
// v = p0 + p1 + bias + resid ; out = alpha*(v-mu)/(std_unbiased+eps) + beta
template <bool OUT_F32, bool OUT_BF16, bool RESID_BF16>
__global__ __launch_bounds__(256)
void norm_kernel(const float* __restrict__ p0, const float* __restrict__ p1,
                 const float* __restrict__ bias, const float* __restrict__ residf,
                 const u16* __restrict__ residb,
                 const float* __restrict__ alpha, const float* __restrict__ beta,
                 float* __restrict__ outf, u16* __restrict__ outb) {
  const int row = blockIdx.x;
  const int tid = threadIdx.x;
  const size_t base = (size_t)row * D_MODEL + tid * 4;
  float4 v0 = *(const float4*)(p0 + base);
  float4 v1 = *(const float4*)(p1 + base);
  float4 bi = *(const float4*)(bias + tid * 4);
  float4 rs;
  if (RESID_BF16) {
    ushort4 rb = *(const ushort4*)(residb + base);
    rs.x = bf2f(rb.x); rs.y = bf2f(rb.y); rs.z = bf2f(rb.z); rs.w = bf2f(rb.w);
  } else {
    rs = *(const float4*)(residf + base);
  }
  float4 v;
  v.x = v0.x + v1.x + bi.x + rs.x;
  v.y = v0.y + v1.y + bi.y + rs.y;
  v.z = v0.z + v1.z + bi.z + rs.z;
  v.w = v0.w + v1.w + bi.w + rs.w;
  float s = v.x + v.y + v.z + v.w;
  float ss = v.x * v.x + v.y * v.y + v.z * v.z + v.w * v.w;
#pragma unroll
  for (int m = 1; m < 64; m <<= 1) {
    s += __shfl_xor(s, m);
    ss += __shfl_xor(ss, m);
  }
  __shared__ float red[8];
  int w = tid >> 6, lane = tid & 63;
  if (lane == 0) { red[w] = s; red[4 + w] = ss; }
  __syncthreads();
  s = red[0] + red[1] + red[2] + red[3];
  ss = red[4] + red[5] + red[6] + red[7];
  float mu = s * (1.0f / 1024.0f);
  float var = fmaxf(ss - s * mu, 0.0f) * (1.0f / 1023.0f);  // unbiased (ddof=1)
  float inv = 1.0f / (sqrtf(var) + 1e-6f);
  float4 a = *(const float4*)(alpha + tid * 4);
  float4 be = *(const float4*)(beta + tid * 4);
  float4 o;
  o.x = (v.x - mu) * inv * a.x + be.x;
  o.y = (v.y - mu) * inv * a.y + be.y;
  o.z = (v.z - mu) * inv * a.z + be.z;
  o.w = (v.w - mu) * inv * a.w + be.w;
  if (OUT_F32) *(float4*)(outf + base) = o;
  if (OUT_BF16) {
    ushort4 ob; ob.x = f2bf(o.x); ob.y = f2bf(o.y); ob.z = f2bf(o.z); ob.w = f2bf(o.w);
    *(ushort4*)(outb + base) = ob;
  }
}

// ---------------------------------------------------------------- launch
extern "C" void kernel_launch(void* const* d_in, const int* in_sizes, int n_in,
                              void* d_out, int out_size, void* d_ws, size_t ws_size,
                              hipStream_t stream) {
  const float* x   = (const float*)d_in[0];
  const float* Wq  = (const float*)d_in[2];
  const float* bq  = (const float*)d_in[3];
  const float* Wk  = (const float*)d_in[4];
  const float* bk  = (const float*)d_in[5];
  const float* Wv  = (const float*)d_in[6];
  const float* bv  = (const float*)d_in[7];
  const float* Wo  = (const float*)d_in[8];
  const float* bo  = (const float*)d_in[9];
  const float* W1  = (const float*)d_in[10];
  const float* b1  = (const float*)d_in[11];
  const float* W2  = (const float*)d_in[12];
  const float* b2  = (const float*)d_in[13];
  const float* a1  = (const float*)d_in[14];
  const float* be1 = (const float*)d_in[15];
  const float* a2  = (const float*)d_in[16];
  const float* be2 = (const float*)d_in[17];

  float* out   = (float*)d_out;
  float* score = out + (size_t)BT * D_MODEL;

  // ws layout (peak 96 MB):
  char* ws = (char*)d_ws;
  const size_t MB = (size_t)1 << 20;
  u16*   xb   = (u16*)(ws + 0 * MB);    // 8   (dead after qkv) -> xnb
  u16*   xnb  = (u16*)(ws + 0 * MB);    // 8   (norm1 out; resid for norm2)
  u16*   WqT  = (u16*)(ws + 8 * MB);    // 2   (dead after qkv)
  u16*   WkT  = (u16*)(ws + 10 * MB);   // 2   (dead after qkv)
  u16*   WvT  = (u16*)(ws + 12 * MB);   // 2   (dead after qkv)
  u16*   WoT  = (u16*)(ws + 14 * MB);   // 2   (dead after Wo)
  u16*   W1T  = (u16*)(ws + 16 * MB);   // 8   (dead after ffn1)
  u16*   W2T  = (u16*)(ws + 24 * MB);   // 8   (dead after ffn2)
  u16*   qw   = (u16*)(ws + 32 * MB);   // 8   (dead after attn)
  u16*   kw   = (u16*)(ws + 40 * MB);   // 8   (dead after attn)
  u16*   vTw  = (u16*)(ws + 48 * MB);   // 8   (dead after attn)
  u16*   valw = (u16*)(ws + 56 * MB);   // 8   (dead after Wo)
  u16*   hw   = (u16*)(ws + 32 * MB);   // 32  (FFN1 out; reuses qw/kw/vTw/valw)
  float* p0   = (float*)(ws + 64 * MB); // 16
  float* p1   = (float*)(ws + 80 * MB); // 16

  // 1) fused prep: x cvt + 6 weight transposes
  {
    PrepArgs pa{ x, xb, Wq, Wk, Wv, Wo, W1, W2, WqT, WkT, WvT, WoT, W1T, W2T };
    prep_kernel<<<16384, 256, 0, stream>>>(pa);
  }

  // 2) QKV projections (one launch, z = q/k/v; Q prescaled by QSCALE)
  {
    GemmArgs ga{};
    ga.A = xb;
    ga.B0 = WqT; ga.B1 = WkT; ga.B2 = WvT;
    ga.bias0 = bq; ga.bias1 = bk; ga.bias2 = bv;
    ga.out0 = qw; ga.out1 = kw; ga.out2 = vTw;
    ga.M = BT; ga.N = D_MODEL; ga.K = D_MODEL;
    gemm_bt<0><<<dim3(8, 32, 3), 256, 0, stream>>>(ga);
  }

  // 3) attention (scores -> d_out, val -> ws)
  attn_kernel<<<1024, 128, 0, stream>>>(qw, kw, vTw, score, valw);

  // 4) Wo projection, split-K=2 -> p0/p1
  {
    GemmArgs ga{};
    ga.A = valw; ga.B0 = WoT; ga.out0 = p0;
    ga.M = BT; ga.N = D_MODEL; ga.K = D_MODEL;
    gemm_bt<3><<<dim3(8, 32, 2), 256, 0, stream>>>(ga);
  }

  // 5) norm1: (p0+p1+bo+x) -> xnb (bf16 only)
  norm_kernel<false, true, false><<<BT, 256, 0, stream>>>(
      p0, p1, bo, x, nullptr, a1, be1, nullptr, xnb);

  // 6) FFN1: relu(xnb @ W1 + b1) -> hw (bf16)
  {
    GemmArgs ga{};
    ga.A = xnb; ga.B0 = W1T; ga.bias0 = b1; ga.out0 = hw;
    ga.M = BT; ga.N = FF_DIM; ga.K = D_MODEL;
    gemm_bt<2><<<dim3(32, 32, 1), 256, 0, stream>>>(ga);
  }

  // 7) FFN2: hw @ W2, split-K=2 -> p0/p1
  {
    GemmArgs ga{};
    ga.A = hw; ga.B0 = W2T; ga.out0 = p0;
    ga.M = BT; ga.N = D_MODEL; ga.K = FF_DIM;
    gemm_bt<3><<<dim3(8, 32, 2), 256, 0, stream>>>(ga);
  }

  // 8) norm2: (p0+p1+b2+xnb) -> out
  norm_kernel<true, false, true><<<BT, 256, 0, stream>>>(
      p0, p1, b2, nullptr, xnb, a2, be2, out, nullptr);
}